// Round 19
// baseline (266.017 us; speedup 1.0000x reference)
//
#include <hip/hip_runtime.h>
#include <hip/hip_bf16.h>
#include <math.h>

// Problem constants (from reference setup_inputs)
#define BB 32
#define NN 1024
#define DD 64
#define TT 2048
#define CHUNKS (TT / 256)   // 8 column-chunks of 256
#define SEGS 16             // n-segments (decoupled scan)

typedef float f32x4 __attribute__((ext_vector_type(4)));
using s16x8 = __attribute__((ext_vector_type(8))) short;   // 8 bf16 (4 VGPRs)

// alpha in LOG2 units: exp() becomes bare v_exp_f32. Validated R9+.
#define NLOG2E_HALF (-0.72134752044448169f)   // -0.5 * log2(e)

__device__ __forceinline__ float exp2_fast(float x) {
    return __builtin_amdgcn_exp2f(x);
}

// DPP move WITHOUT tied-old operand -> fuses into the consumer op.
template<int CTRL>
__device__ __forceinline__ float dpp_mov_f(float v) {
    return __int_as_float(
        __builtin_amdgcn_mov_dpp(__float_as_int(v), CTRL, 0xF, 0xF, true));
}

template<int GB>
__device__ __forceinline__ float groupMax(float v) {
    v = fmaxf(v, dpp_mov_f<0x0B1>(v));  // xor1
    v = fmaxf(v, dpp_mov_f<0x04E>(v));  // xor2
    v = fmaxf(v, dpp_mov_f<0x141>(v));  // xor4 (row_half_mirror)
    v = fmaxf(v, dpp_mov_f<0x140>(v));  // xor8 (row_mirror)
    if constexpr (GB == 6) {
        v = fmaxf(v, __shfl_xor(v, 16));
        v = fmaxf(v, __shfl_xor(v, 32));
    }
    return v;
}

template<int GB>
__device__ __forceinline__ float groupSum(float v) {
    v += dpp_mov_f<0x0B1>(v);
    v += dpp_mov_f<0x04E>(v);
    v += dpp_mov_f<0x141>(v);
    v += dpp_mov_f<0x140>(v);
    if constexpr (GB == 6) {
        v += __shfl_xor(v, 16);
        v += __shfl_xor(v, 32);
    }
    return v;
}

// bf16 round-to-nearest-even split: x ~= hi + lo, |x-hi-lo| <= 2^-18 |x|.
__device__ __forceinline__ unsigned short bf16_rne(float x) {
    unsigned u = __float_as_uint(x);
    return (unsigned short)((u + 0x7FFFu + ((u >> 16) & 1u)) >> 16);
}
__device__ __forceinline__ void bf16_split(float x, short& hi, short& lo) {
    const unsigned short h = bf16_rne(x);
    const float xh = __uint_as_float(((unsigned)h) << 16);
    hi = (short)h;
    lo = (short)bf16_rne(x - xh);
}

__device__ __forceinline__ void loadW(const float* __restrict__ W, int col,
                                      f32x4* wv) {
#pragma unroll
    for (int i = 0; i < 16; ++i) {
        wv[i].x = W[(size_t)(4 * i + 0) * TT + col];
        wv[i].y = W[(size_t)(4 * i + 1) * TT + col];
        wv[i].z = W[(size_t)(4 * i + 2) * TT + col];
        wv[i].w = W[(size_t)(4 * i + 3) * TT + col];
    }
}

__device__ __forceinline__ float hsum(f32x4 s) {
    return (s.x + s.y) + (s.z + s.w);
}

// Scalar dot4 (segsum + fallback). Plain __restrict__ pointers: scalar
// s_load path for x (R17 lesson: forcing the vector path is 3x worse).
__device__ __forceinline__ void dot4(const float* __restrict__ x0p,
                                     const f32x4* wv, float* xw) {
    const f32x4* xr0 = (const f32x4*)(x0p);
    const f32x4* xr1 = (const f32x4*)(x0p + DD);
    const f32x4* xr2 = (const f32x4*)(x0p + 2 * DD);
    const f32x4* xr3 = (const f32x4*)(x0p + 3 * DD);
    f32x4 s0 = {0.f, 0.f, 0.f, 0.f};
    f32x4 s1 = {0.f, 0.f, 0.f, 0.f};
    f32x4 s2 = {0.f, 0.f, 0.f, 0.f};
    f32x4 s3 = {0.f, 0.f, 0.f, 0.f};
#pragma unroll
    for (int i = 0; i < 16; ++i) {
        const f32x4 w = wv[i];
        s0 += xr0[i] * w;
        s1 += xr1[i] * w;
        s2 += xr2[i] * w;
        s3 += xr3[i] * w;
    }
    xw[0] = hsum(s0); xw[1] = hsum(s1); xw[2] = hsum(s2); xw[3] = hsum(s3);
}

// Pass A: per-(b, t, segment) sum of log-probs (log2 units). At its issue
// floor (~65 us, R5) — unchanged.
template<int SEG>
__global__ __launch_bounds__(256, 4)
void segsum_kernel(const float* __restrict__ data,
                   const float* __restrict__ targets,
                   const float* __restrict__ W,
                   float* __restrict__ segsum)
{
    constexpr int NSEG = NN / SEG;
    const int blk   = blockIdx.x;
    const int s     = blk % SEG;
    const int rem   = blk / SEG;
    const int chunk = rem % CHUNKS;
    const int b     = rem / CHUNKS;
    const int tid   = threadIdx.x;
    const int col   = chunk * 256 + tid;

    f32x4 wv[16];
    loadW(W, col, wv);

    const float* xb = data + (size_t)b * NN * DD;
    const float* tb = targets + (size_t)b * NN;

    const int n0 = s * NSEG;
    float acc = 0.0f;
    for (int n = n0; n < n0 + NSEG; n += 4) {
        float xw[4];
        dot4(xb + (size_t)n * DD, wv, xw);
#pragma unroll
        for (int j = 0; j < 4; ++j) {
            const float d = tb[n + j] - xw[j];
            acc = fmaf(d * d, NLOG2E_HALF, acc);
        }
    }
    segsum[((size_t)b * SEG + s) * TT + col] = acc;
}

// Pass B: MFMA scan, MT=16 tile (16.6 KB LDS -> ~2x resident blocks vs
// R18's 33 KB). Per block (b, seg, 256-col chunk):
//   phase A: xw tile [16 points][256 cols] via mfma_f32_16x16x32_bf16,
//            hi/lo split, 3 products (lo*lo dropped: ~2^-32 relative).
//   phase B: softmax quad loop reading xw from LDS.
// Fragment layouts (guide §3, m89-verified):
//   A: row = lane&15, k = (lane>>4)*8 + j;  B: col = lane&15, same k
//   C/D: col = lane&15, row = (lane>>4)*4 + reg
template<int SEG, int GB>
__global__ __launch_bounds__(256)
void scan_mfma_kernel(const float* __restrict__ data,
                      const float* __restrict__ targets,
                      const float* __restrict__ W,
                      const float* __restrict__ segsum,
                      float* __restrict__ mP,
                      float* __restrict__ sP,
                      float* __restrict__ pP)
{
    constexpr int NSEG = NN / SEG;            // 64
    constexpr int MT   = 16;                  // points per tile
    constexpr int LDSW = 260;                 // padded row stride (floats)
    constexpr int PPN  = TT >> GB;

    __shared__ __align__(16) float xw_tile[MT][LDSW];   // 16.6 KB

    const int blk   = blockIdx.x;
    const int s     = blk % SEG;
    const int rem   = blk / SEG;
    const int chunk = rem % CHUNKS;
    const int b     = rem / CHUNKS;
    const int tid   = threadIdx.x;
    const int wv    = tid >> 6;               // wave 0..3 -> 64-col quarter
    const int l     = tid & 63;
    const int col   = chunk * 256 + tid;      // softmax column of this thread

    const float* xb = data + (size_t)b * NN * DD;
    const float* tb = targets + (size_t)b * NN;

    // ---- B (W) fragments for this wave's quarter, hi/lo, loaded once ----
    s16x8 bh[2][4], bl[2][4];                 // [kstep][ntile]
    {
        const int c0 = chunk * 256 + wv * 64 + (l & 15);
        const int kb = (l >> 4) * 8;
#pragma unroll
        for (int ks = 0; ks < 2; ++ks)
#pragma unroll
            for (int nt = 0; nt < 4; ++nt) {
                const int cw = c0 + nt * 16;
#pragma unroll
                for (int j = 0; j < 8; ++j) {
                    short h, lo_;
                    bf16_split(W[(size_t)(ks * 32 + kb + j) * TT + cw], h, lo_);
                    bh[ks][nt][j] = h;
                    bl[ks][nt][j] = lo_;
                }
            }
    }

    const int  k16    = (chunk * 256 + (tid & ~((1 << GB) - 1))) >> GB;
    const bool writer = (l & ((1 << GB) - 1)) == 0;
    const size_t base0 = (size_t)b * NN * PPN + k16;

    // exclusive segment prefix (log2 units)
    float alpha = 0.0f;
    if constexpr (SEG > 1) {
        for (int s2 = 0; s2 < s; ++s2)
            alpha += segsum[((size_t)b * SEG + s2) * TT + col];
    }

    const int n0 = s * NSEG;

#pragma unroll 1
    for (int h = 0; h < NSEG / MT; ++h) {
        // ---------- phase A: MFMA xw tile ----------
        f32x4 acc[4];
#pragma unroll
        for (int nt = 0; nt < 4; ++nt) acc[nt] = (f32x4){0.f, 0.f, 0.f, 0.f};

#pragma unroll
        for (int ks = 0; ks < 2; ++ks) {
            s16x8 ah, al;
            {
                const int row = n0 + h * MT + (l & 15);
                const int kb  = ks * 32 + (l >> 4) * 8;
#pragma unroll
                for (int j = 0; j < 8; ++j) {
                    short hh, ll;
                    bf16_split(xb[(size_t)row * DD + kb + j], hh, ll);
                    ah[j] = hh; al[j] = ll;
                }
            }
#pragma unroll
            for (int nt = 0; nt < 4; ++nt) {
                acc[nt] = __builtin_amdgcn_mfma_f32_16x16x32_bf16(ah, bh[ks][nt], acc[nt], 0, 0, 0);
                acc[nt] = __builtin_amdgcn_mfma_f32_16x16x32_bf16(ah, bl[ks][nt], acc[nt], 0, 0, 0);
                acc[nt] = __builtin_amdgcn_mfma_f32_16x16x32_bf16(al, bh[ks][nt], acc[nt], 0, 0, 0);
            }
        }

        // C -> LDS (row = (l>>4)*4 + r, col = wv*64 + nt*16 + (l&15))
#pragma unroll
        for (int nt = 0; nt < 4; ++nt)
#pragma unroll
            for (int r = 0; r < 4; ++r)
                xw_tile[(l >> 4) * 4 + r][wv * 64 + nt * 16 + (l & 15)] = acc[nt][r];

        __syncthreads();

        // ---------- phase B: softmax for these 16 points ----------
#pragma unroll 1
        for (int q = 0; q < MT; q += 4) {
            const int n = n0 + h * MT + q;
            float xw[4];
#pragma unroll
            for (int j = 0; j < 4; ++j) xw[j] = xw_tile[q + j][tid];

            float a[4];
            float al_ = alpha;
#pragma unroll
            for (int j = 0; j < 4; ++j) {
                a[j] = al_;
                const float d = tb[n + j] - xw[j];
                al_ = fmaf(d * d, NLOG2E_HALF, al_);
            }
            alpha = al_;

            float m[4], e[4], qv[4], sv[4], pv[4];
#pragma unroll
            for (int j = 0; j < 4; ++j) m[j] = groupMax<GB>(a[j]);
#pragma unroll
            for (int j = 0; j < 4; ++j) {
                e[j]  = exp2_fast(a[j] - m[j]);
                qv[j] = e[j] * xw[j];
            }
#pragma unroll
            for (int j = 0; j < 4; ++j) sv[j] = groupSum<GB>(e[j]);
#pragma unroll
            for (int j = 0; j < 4; ++j) pv[j] = groupSum<GB>(qv[j]);

            if (writer) {
                const size_t i0 = base0 + (size_t)n * PPN;
#pragma unroll
                for (int j = 0; j < 4; ++j) {
                    mP[i0 + (size_t)j * PPN] = m[j];
                    sP[i0 + (size_t)j * PPN] = sv[j];
                    pP[i0 + (size_t)j * PPN] = pv[j];
                }
            }
        }
        __syncthreads();
    }
}

// Single-stream scalar scan (fallback path only; R14 form).
template<int SEG, int GB>
__global__ __launch_bounds__(256, 4)
void scan_kernel(const float* __restrict__ data,
                 const float* __restrict__ targets,
                 const float* __restrict__ W,
                 const float* __restrict__ segsum,
                 float* __restrict__ mP,
                 float* __restrict__ sP,
                 float* __restrict__ pP)
{
    constexpr int NSEG = NN / SEG;
    constexpr int PPN  = TT >> GB;
    const int blk   = blockIdx.x;
    const int s     = blk % SEG;
    const int rem   = blk / SEG;
    const int chunk = rem % CHUNKS;
    const int b     = rem / CHUNKS;
    const int tid   = threadIdx.x;
    const int lane  = tid & 63;
    const int col   = chunk * 256 + tid;

    f32x4 wv[16];
    loadW(W, col, wv);

    const float* xb = data + (size_t)b * NN * DD;
    const float* tb = targets + (size_t)b * NN;

    const int  k      = (chunk * 256 + (tid & ~((1 << GB) - 1))) >> GB;
    const bool writer = (lane & ((1 << GB) - 1)) == 0;
    const size_t base0 = (size_t)b * NN * PPN + k;

    float alpha = 0.0f;
    if constexpr (SEG > 1) {
        for (int s2 = 0; s2 < s; ++s2)
            alpha += segsum[((size_t)b * SEG + s2) * TT + col];
    }

    const int n0 = s * NSEG;
    for (int n = n0; n < n0 + NSEG; n += 4) {
        float xw[4];
        dot4(xb + (size_t)n * DD, wv, xw);
        float a[4];
        float al = alpha;
#pragma unroll
        for (int j = 0; j < 4; ++j) {
            a[j] = al;
            const float d = tb[n + j] - xw[j];
            al = fmaf(d * d, NLOG2E_HALF, al);
        }
        alpha = al;
        float m[4], e[4], qv[4], sv[4], pv[4];
#pragma unroll
        for (int j = 0; j < 4; ++j) m[j] = groupMax<GB>(a[j]);
#pragma unroll
        for (int j = 0; j < 4; ++j) {
            e[j]  = exp2_fast(a[j] - m[j]);
            qv[j] = e[j] * xw[j];
        }
#pragma unroll
        for (int j = 0; j < 4; ++j) sv[j] = groupSum<GB>(e[j]);
#pragma unroll
        for (int j = 0; j < 4; ++j) pv[j] = groupSum<GB>(qv[j]);
        if (writer) {
            const size_t i0 = base0 + (size_t)n * PPN;
#pragma unroll
            for (int j = 0; j < 4; ++j) {
                mP[i0 + (size_t)j * PPN] = m[j];
                sP[i0 + (size_t)j * PPN] = sv[j];
                pP[i0 + (size_t)j * PPN] = pv[j];
            }
        }
    }
}

// Pass C: one wave per (b,n): merge PPN partials (log2 units).
template<int PPN>
__global__ __launch_bounds__(256)
void combine_kernel(const float* __restrict__ mP,
                    const float* __restrict__ sP,
                    const float* __restrict__ pP,
                    float* __restrict__ out)
{
    const int wgid = blockIdx.x * 4 + (threadIdx.x >> 6);   // = b*NN + n
    const int lane = threadIdx.x & 63;
    const size_t base = (size_t)wgid * PPN;

    float m = -INFINITY, s = 0.0f, p = 0.0f;
    if constexpr (PPN >= 64) {
#pragma unroll
        for (int j = 0; j < PPN / 64; ++j) {
            const size_t idx = base + lane + j * 64;
            const float mk = mP[idx], sk = sP[idx], pk = pP[idx];
            const float M  = fmaxf(m, mk);
            const float e1 = exp2_fast(m - M), e2 = exp2_fast(mk - M);
            s = s * e1 + sk * e2;
            p = p * e1 + pk * e2;
            m = M;
        }
    } else {
        if (lane < PPN) {
            m = mP[base + lane]; s = sP[base + lane]; p = pP[base + lane];
        }
    }

#pragma unroll
    for (int off = 1; off < 64; off <<= 1) {
        const float mo = __shfl_xor(m, off);
        const float so = __shfl_xor(s, off);
        const float po = __shfl_xor(p, off);
        const float M  = fmaxf(m, mo);
        const float e1 = exp2_fast(m - M), e2 = exp2_fast(mo - M);
        s = s * e1 + so * e2;
        p = p * e1 + po * e2;
        m = M;
    }

    if (lane == 0) out[wgid] = p / s;
}

extern "C" void kernel_launch(void* const* d_in, const int* in_sizes, int n_in,
                              void* d_out, int out_size, void* d_ws, size_t ws_size,
                              hipStream_t stream)
{
    (void)in_sizes; (void)n_in; (void)out_size;
    const float* data    = (const float*)d_in[0];
    const float* targets = (const float*)d_in[1];
    const float* W       = (const float*)d_in[2];
    float* out = (float*)d_out;

    const size_t plane4 = (size_t)BB * NN * (TT >> 4);   // GB=4: 128 partials/(b,n)
    const size_t plane6 = (size_t)BB * NN * (TT >> 6);   // GB=6: 32 partials/(b,n)
    const size_t seg16  = (size_t)BB * SEGS * TT;

    const int scan_grid = BB * SEGS * CHUNKS;            // 4096 blocks of 256

    if (ws_size >= (3 * plane4 + seg16) * sizeof(float)) {
        // ~54 MB path: SEG=16, GB=4, MFMA scan (MT=16)
        float* mP = (float*)d_ws;
        float* sP = mP + plane4;
        float* pP = sP + plane4;
        float* sg = pP + plane4;
        segsum_kernel<SEGS><<<BB * CHUNKS * SEGS, 256, 0, stream>>>(data, targets, W, sg);
        scan_mfma_kernel<SEGS, 4><<<scan_grid, 256, 0, stream>>>(data, targets, W, sg, mP, sP, pP);
        combine_kernel<128><<<(BB * NN) / 4, 256, 0, stream>>>(mP, sP, pP, out);
    } else if (ws_size >= (3 * plane6 + seg16) * sizeof(float)) {
        // ~17 MB path: SEG=16, GB=6, MFMA scan
        float* mP = (float*)d_ws;
        float* sP = mP + plane6;
        float* pP = sP + plane6;
        float* sg = pP + plane6;
        segsum_kernel<SEGS><<<BB * CHUNKS * SEGS, 256, 0, stream>>>(data, targets, W, sg);
        scan_mfma_kernel<SEGS, 6><<<scan_grid, 256, 0, stream>>>(data, targets, W, sg, mP, sP, pP);
        combine_kernel<32><<<(BB * NN) / 4, 256, 0, stream>>>(mP, sP, pP, out);
    } else {
        // 12 MB fallback: no segmentation (slow but correct)
        float* mP = (float*)d_ws;
        float* sP = mP + plane6;
        float* pP = sP + plane6;
        scan_kernel<1, 6><<<BB * CHUNKS, 256, 0, stream>>>(data, targets, W, nullptr, mP, sP, pP);
        combine_kernel<32><<<(BB * NN) / 4, 256, 0, stream>>>(mP, sP, pP, out);
    }
}

// Round 20
// 207.737 us; speedup vs baseline: 1.2806x; 1.2806x over previous
//
#include <hip/hip_runtime.h>
#include <hip/hip_bf16.h>
#include <math.h>

// Problem constants (from reference setup_inputs)
#define BB 32
#define NN 1024
#define DD 64
#define TT 2048
#define CHUNKS (TT / 256)   // 8 column-chunks of 256
#define SEGS 16             // n-segments (decoupled scan)

typedef float f32x4 __attribute__((ext_vector_type(4)));
using s16x8 = __attribute__((ext_vector_type(8))) short;   // 8 bf16 (4 VGPRs)

// alpha in LOG2 units: exp() becomes bare v_exp_f32. Validated R9+.
#define NLOG2E_HALF (-0.72134752044448169f)   // -0.5 * log2(e)

__device__ __forceinline__ float exp2_fast(float x) {
    return __builtin_amdgcn_exp2f(x);
}

// DPP move WITHOUT tied-old operand -> fuses into the consumer op.
template<int CTRL>
__device__ __forceinline__ float dpp_mov_f(float v) {
    return __int_as_float(
        __builtin_amdgcn_mov_dpp(__float_as_int(v), CTRL, 0xF, 0xF, true));
}

template<int GB>
__device__ __forceinline__ float groupMax(float v) {
    v = fmaxf(v, dpp_mov_f<0x0B1>(v));  // xor1
    v = fmaxf(v, dpp_mov_f<0x04E>(v));  // xor2
    v = fmaxf(v, dpp_mov_f<0x141>(v));  // xor4 (row_half_mirror)
    v = fmaxf(v, dpp_mov_f<0x140>(v));  // xor8 (row_mirror)
    if constexpr (GB == 6) {
        v = fmaxf(v, __shfl_xor(v, 16));
        v = fmaxf(v, __shfl_xor(v, 32));
    }
    return v;
}

template<int GB>
__device__ __forceinline__ float groupSum(float v) {
    v += dpp_mov_f<0x0B1>(v);
    v += dpp_mov_f<0x04E>(v);
    v += dpp_mov_f<0x141>(v);
    v += dpp_mov_f<0x140>(v);
    if constexpr (GB == 6) {
        v += __shfl_xor(v, 16);
        v += __shfl_xor(v, 32);
    }
    return v;
}

// bf16 round-to-nearest-even split: x ~= hi + lo, |x-hi-lo| <= 2^-18 |x|.
__device__ __forceinline__ unsigned short bf16_rne(float x) {
    unsigned u = __float_as_uint(x);
    return (unsigned short)((u + 0x7FFFu + ((u >> 16) & 1u)) >> 16);
}
__device__ __forceinline__ void bf16_split(float x, short& hi, short& lo) {
    const unsigned short h = bf16_rne(x);
    const float xh = __uint_as_float(((unsigned)h) << 16);
    hi = (short)h;
    lo = (short)bf16_rne(x - xh);
}

typedef float f32x4v __attribute__((ext_vector_type(4)));

__device__ __forceinline__ void loadW(const float* __restrict__ W, int col,
                                      f32x4* wv) {
#pragma unroll
    for (int i = 0; i < 16; ++i) {
        wv[i].x = W[(size_t)(4 * i + 0) * TT + col];
        wv[i].y = W[(size_t)(4 * i + 1) * TT + col];
        wv[i].z = W[(size_t)(4 * i + 2) * TT + col];
        wv[i].w = W[(size_t)(4 * i + 3) * TT + col];
    }
}

__device__ __forceinline__ float hsum(f32x4 s) {
    return (s.x + s.y) + (s.z + s.w);
}

// Scalar dot4 (fallback only).
__device__ __forceinline__ void dot4(const float* __restrict__ x0p,
                                     const f32x4* wv, float* xw) {
    const f32x4* xr0 = (const f32x4*)(x0p);
    const f32x4* xr1 = (const f32x4*)(x0p + DD);
    const f32x4* xr2 = (const f32x4*)(x0p + 2 * DD);
    const f32x4* xr3 = (const f32x4*)(x0p + 3 * DD);
    f32x4 s0 = {0.f, 0.f, 0.f, 0.f};
    f32x4 s1 = {0.f, 0.f, 0.f, 0.f};
    f32x4 s2 = {0.f, 0.f, 0.f, 0.f};
    f32x4 s3 = {0.f, 0.f, 0.f, 0.f};
#pragma unroll
    for (int i = 0; i < 16; ++i) {
        const f32x4 w = wv[i];
        s0 += xr0[i] * w;
        s1 += xr1[i] * w;
        s2 += xr2[i] * w;
        s3 += xr3[i] * w;
    }
    xw[0] = hsum(s0); xw[1] = hsum(s1); xw[2] = hsum(s2); xw[3] = hsum(s3);
}

// Load this wave's B (W) fragments, hi/lo split (R18-verified layout:
// B col = lane&15 (+nt*16+wv*64), k = ks*32 + (lane>>4)*8 + j).
__device__ __forceinline__ void loadB(const float* __restrict__ W,
                                      int chunk, int wv, int l,
                                      s16x8 bh[2][4], s16x8 bl[2][4]) {
    const int c0 = chunk * 256 + wv * 64 + (l & 15);
    const int kb = (l >> 4) * 8;
#pragma unroll
    for (int ks = 0; ks < 2; ++ks)
#pragma unroll
        for (int nt = 0; nt < 4; ++nt) {
            const int cw = c0 + nt * 16;
#pragma unroll
            for (int j = 0; j < 8; ++j) {
                short h, lo_;
                bf16_split(W[(size_t)(ks * 32 + kb + j) * TT + cw], h, lo_);
                bh[ks][nt][j] = h;
                bl[ks][nt][j] = lo_;
            }
        }
}

// MFMA a 32x256 xw tile into acc[mt][nt] (3-product hi/lo split; lo*lo
// dropped ~2^-32). Rows = tile_n0 + mt*16 + (l&15) pattern per layout.
__device__ __forceinline__ void mfma_tile(const float* __restrict__ xb,
                                          int tile_n0, int l,
                                          const s16x8 bh[2][4],
                                          const s16x8 bl[2][4],
                                          f32x4 acc[2][4]) {
#pragma unroll
    for (int mt = 0; mt < 2; ++mt)
#pragma unroll
        for (int nt = 0; nt < 4; ++nt) acc[mt][nt] = (f32x4){0.f, 0.f, 0.f, 0.f};
#pragma unroll
    for (int ks = 0; ks < 2; ++ks) {
        s16x8 ah[2], al[2];
#pragma unroll
        for (int mt = 0; mt < 2; ++mt) {
            const int row = tile_n0 + mt * 16 + (l & 15);
            const int kb  = ks * 32 + (l >> 4) * 8;
#pragma unroll
            for (int j = 0; j < 8; ++j) {
                short hh, ll;
                bf16_split(xb[(size_t)row * DD + kb + j], hh, ll);
                ah[mt][j] = hh; al[mt][j] = ll;
            }
        }
#pragma unroll
        for (int mt = 0; mt < 2; ++mt)
#pragma unroll
            for (int nt = 0; nt < 4; ++nt) {
                acc[mt][nt] = __builtin_amdgcn_mfma_f32_16x16x32_bf16(ah[mt], bh[ks][nt], acc[mt][nt], 0, 0, 0);
                acc[mt][nt] = __builtin_amdgcn_mfma_f32_16x16x32_bf16(ah[mt], bl[ks][nt], acc[mt][nt], 0, 0, 0);
                acc[mt][nt] = __builtin_amdgcn_mfma_f32_16x16x32_bf16(al[mt], bh[ks][nt], acc[mt][nt], 0, 0, 0);
            }
    }
}

// Pass A (MFMA): per-(b, chunk, segment) sum of log-probs, fully in
// registers. C layout gives thread l rows (l>>4)*4+r (+16*mt) of cols
// (l&15)+16*nt+64*wv; local column partial over its 16 of 64 rows, then
// shfl_xor(16)+shfl_xor(32) completes the column sum. No LDS tile.
template<int SEG>
__global__ __launch_bounds__(256)
void segsum_mfma_kernel(const float* __restrict__ data,
                        const float* __restrict__ targets,
                        const float* __restrict__ W,
                        float* __restrict__ segsum)
{
    constexpr int NSEG = NN / SEG;            // 64
    __shared__ float ts[NSEG];

    const int blk   = blockIdx.x;
    const int s     = blk % SEG;
    const int rem   = blk / SEG;
    const int chunk = rem % CHUNKS;
    const int b     = rem / CHUNKS;
    const int tid   = threadIdx.x;
    const int wv    = tid >> 6;
    const int l     = tid & 63;

    const float* xb = data + (size_t)b * NN * DD;
    const float* tb = targets + (size_t)b * NN;
    const int n0 = s * NSEG;

    if (tid < NSEG) ts[tid] = tb[n0 + tid];

    s16x8 bh[2][4], bl[2][4];
    loadB(W, chunk, wv, l, bh, bl);
    __syncthreads();

    float colacc[4] = {0.f, 0.f, 0.f, 0.f};

#pragma unroll 1
    for (int h = 0; h < NSEG / 32; ++h) {
        f32x4 acc[2][4];
        mfma_tile(xb, n0 + h * 32, l, bh, bl, acc);
#pragma unroll
        for (int mt = 0; mt < 2; ++mt)
#pragma unroll
            for (int r = 0; r < 4; ++r) {
                const float tv = ts[h * 32 + mt * 16 + (l >> 4) * 4 + r];
#pragma unroll
                for (int nt = 0; nt < 4; ++nt) {
                    const float d = tv - acc[mt][nt][r];
                    colacc[nt] = fmaf(d * d, NLOG2E_HALF, colacc[nt]);
                }
            }
    }

    // complete column sums across the 4 row-groups
#pragma unroll
    for (int nt = 0; nt < 4; ++nt) {
        colacc[nt] += __shfl_xor(colacc[nt], 16);
        colacc[nt] += __shfl_xor(colacc[nt], 32);
    }

    if (l < 16) {
        const size_t base = ((size_t)b * SEG + s) * TT + chunk * 256 + wv * 64 + l;
#pragma unroll
        for (int nt = 0; nt < 4; ++nt) segsum[base + nt * 16] = colacc[nt];
    }
}

// Pass B: MFMA scan (R18 structure, MT=32 — best measured).
template<int SEG, int GB>
__global__ __launch_bounds__(256)
void scan_mfma_kernel(const float* __restrict__ data,
                      const float* __restrict__ targets,
                      const float* __restrict__ W,
                      const float* __restrict__ segsum,
                      float* __restrict__ mP,
                      float* __restrict__ sP,
                      float* __restrict__ pP)
{
    constexpr int NSEG = NN / SEG;            // 64
    constexpr int MT   = 32;                  // points per tile
    constexpr int LDSW = 260;                 // padded row stride (floats)
    constexpr int PPN  = TT >> GB;

    __shared__ __align__(16) float xw_tile[MT][LDSW];   // 33.3 KB

    const int blk   = blockIdx.x;
    const int s     = blk % SEG;
    const int rem   = blk / SEG;
    const int chunk = rem % CHUNKS;
    const int b     = rem / CHUNKS;
    const int tid   = threadIdx.x;
    const int wv    = tid >> 6;               // wave 0..3 -> 64-col quarter
    const int l     = tid & 63;
    const int col   = chunk * 256 + tid;      // softmax column of this thread

    const float* xb = data + (size_t)b * NN * DD;
    const float* tb = targets + (size_t)b * NN;

    s16x8 bh[2][4], bl[2][4];
    loadB(W, chunk, wv, l, bh, bl);

    const int  k16    = (chunk * 256 + (tid & ~((1 << GB) - 1))) >> GB;
    const bool writer = (l & ((1 << GB) - 1)) == 0;
    const size_t base0 = (size_t)b * NN * PPN + k16;

    // exclusive segment prefix (log2 units)
    float alpha = 0.0f;
    if constexpr (SEG > 1) {
        for (int s2 = 0; s2 < s; ++s2)
            alpha += segsum[((size_t)b * SEG + s2) * TT + col];
    }

    const int n0 = s * NSEG;

#pragma unroll 1
    for (int h = 0; h < NSEG / MT; ++h) {
        // ---------- phase A: MFMA xw tile ----------
        f32x4 acc[2][4];
        mfma_tile(xb, n0 + h * MT, l, bh, bl, acc);

        // C -> LDS (row = mt*16 + (l>>4)*4 + r, col = wv*64 + nt*16 + (l&15))
#pragma unroll
        for (int mt = 0; mt < 2; ++mt)
#pragma unroll
            for (int nt = 0; nt < 4; ++nt)
#pragma unroll
                for (int r = 0; r < 4; ++r)
                    xw_tile[mt * 16 + (l >> 4) * 4 + r][wv * 64 + nt * 16 + (l & 15)] = acc[mt][nt][r];

        __syncthreads();

        // ---------- phase B: softmax for these 32 points ----------
#pragma unroll 1
        for (int q = 0; q < MT; q += 4) {
            const int n = n0 + h * MT + q;
            float xw[4];
#pragma unroll
            for (int j = 0; j < 4; ++j) xw[j] = xw_tile[q + j][tid];

            float a[4];
            float al_ = alpha;
#pragma unroll
            for (int j = 0; j < 4; ++j) {
                a[j] = al_;
                const float d = tb[n + j] - xw[j];
                al_ = fmaf(d * d, NLOG2E_HALF, al_);
            }
            alpha = al_;

            float m[4], e[4], qv[4], sv[4], pv[4];
#pragma unroll
            for (int j = 0; j < 4; ++j) m[j] = groupMax<GB>(a[j]);
#pragma unroll
            for (int j = 0; j < 4; ++j) {
                e[j]  = exp2_fast(a[j] - m[j]);
                qv[j] = e[j] * xw[j];
            }
#pragma unroll
            for (int j = 0; j < 4; ++j) sv[j] = groupSum<GB>(e[j]);
#pragma unroll
            for (int j = 0; j < 4; ++j) pv[j] = groupSum<GB>(qv[j]);

            if (writer) {
                const size_t i0 = base0 + (size_t)n * PPN;
#pragma unroll
                for (int j = 0; j < 4; ++j) {
                    mP[i0 + (size_t)j * PPN] = m[j];
                    sP[i0 + (size_t)j * PPN] = sv[j];
                    pP[i0 + (size_t)j * PPN] = pv[j];
                }
            }
        }
        __syncthreads();
    }
}

// Single-stream scalar scan (fallback path only; R14 form).
template<int SEG, int GB>
__global__ __launch_bounds__(256, 4)
void scan_kernel(const float* __restrict__ data,
                 const float* __restrict__ targets,
                 const float* __restrict__ W,
                 const float* __restrict__ segsum,
                 float* __restrict__ mP,
                 float* __restrict__ sP,
                 float* __restrict__ pP)
{
    constexpr int NSEG = NN / SEG;
    constexpr int PPN  = TT >> GB;
    const int blk   = blockIdx.x;
    const int s     = blk % SEG;
    const int rem   = blk / SEG;
    const int chunk = rem % CHUNKS;
    const int b     = rem / CHUNKS;
    const int tid   = threadIdx.x;
    const int lane  = tid & 63;
    const int col   = chunk * 256 + tid;

    f32x4 wv[16];
    loadW(W, col, wv);

    const float* xb = data + (size_t)b * NN * DD;
    const float* tb = targets + (size_t)b * NN;

    const int  k      = (chunk * 256 + (tid & ~((1 << GB) - 1))) >> GB;
    const bool writer = (lane & ((1 << GB) - 1)) == 0;
    const size_t base0 = (size_t)b * NN * PPN + k;

    float alpha = 0.0f;
    if constexpr (SEG > 1) {
        for (int s2 = 0; s2 < s; ++s2)
            alpha += segsum[((size_t)b * SEG + s2) * TT + col];
    }

    const int n0 = s * NSEG;
    for (int n = n0; n < n0 + NSEG; n += 4) {
        float xw[4];
        dot4(xb + (size_t)n * DD, wv, xw);
        float a[4];
        float al = alpha;
#pragma unroll
        for (int j = 0; j < 4; ++j) {
            a[j] = al;
            const float d = tb[n + j] - xw[j];
            al = fmaf(d * d, NLOG2E_HALF, al);
        }
        alpha = al;
        float m[4], e[4], qv[4], sv[4], pv[4];
#pragma unroll
        for (int j = 0; j < 4; ++j) m[j] = groupMax<GB>(a[j]);
#pragma unroll
        for (int j = 0; j < 4; ++j) {
            e[j]  = exp2_fast(a[j] - m[j]);
            qv[j] = e[j] * xw[j];
        }
#pragma unroll
        for (int j = 0; j < 4; ++j) sv[j] = groupSum<GB>(e[j]);
#pragma unroll
        for (int j = 0; j < 4; ++j) pv[j] = groupSum<GB>(qv[j]);
        if (writer) {
            const size_t i0 = base0 + (size_t)n * PPN;
#pragma unroll
            for (int j = 0; j < 4; ++j) {
                mP[i0 + (size_t)j * PPN] = m[j];
                sP[i0 + (size_t)j * PPN] = sv[j];
                pP[i0 + (size_t)j * PPN] = pv[j];
            }
        }
    }
}

// Pass C: one wave per (b,n): merge PPN partials (log2 units).
template<int PPN>
__global__ __launch_bounds__(256)
void combine_kernel(const float* __restrict__ mP,
                    const float* __restrict__ sP,
                    const float* __restrict__ pP,
                    float* __restrict__ out)
{
    const int wgid = blockIdx.x * 4 + (threadIdx.x >> 6);   // = b*NN + n
    const int lane = threadIdx.x & 63;
    const size_t base = (size_t)wgid * PPN;

    float m = -INFINITY, s = 0.0f, p = 0.0f;
    if constexpr (PPN >= 64) {
#pragma unroll
        for (int j = 0; j < PPN / 64; ++j) {
            const size_t idx = base + lane + j * 64;
            const float mk = mP[idx], sk = sP[idx], pk = pP[idx];
            const float M  = fmaxf(m, mk);
            const float e1 = exp2_fast(m - M), e2 = exp2_fast(mk - M);
            s = s * e1 + sk * e2;
            p = p * e1 + pk * e2;
            m = M;
        }
    } else {
        if (lane < PPN) {
            m = mP[base + lane]; s = sP[base + lane]; p = pP[base + lane];
        }
    }

#pragma unroll
    for (int off = 1; off < 64; off <<= 1) {
        const float mo = __shfl_xor(m, off);
        const float so = __shfl_xor(s, off);
        const float po = __shfl_xor(p, off);
        const float M  = fmaxf(m, mo);
        const float e1 = exp2_fast(m - M), e2 = exp2_fast(mo - M);
        s = s * e1 + so * e2;
        p = p * e1 + po * e2;
        m = M;
    }

    if (lane == 0) out[wgid] = p / s;
}

extern "C" void kernel_launch(void* const* d_in, const int* in_sizes, int n_in,
                              void* d_out, int out_size, void* d_ws, size_t ws_size,
                              hipStream_t stream)
{
    (void)in_sizes; (void)n_in; (void)out_size;
    const float* data    = (const float*)d_in[0];
    const float* targets = (const float*)d_in[1];
    const float* W       = (const float*)d_in[2];
    float* out = (float*)d_out;

    const size_t plane4 = (size_t)BB * NN * (TT >> 4);   // GB=4: 128 partials/(b,n)
    const size_t plane6 = (size_t)BB * NN * (TT >> 6);   // GB=6: 32 partials/(b,n)
    const size_t seg16  = (size_t)BB * SEGS * TT;

    const int grid = BB * SEGS * CHUNKS;                 // 4096 blocks of 256

    if (ws_size >= (3 * plane4 + seg16) * sizeof(float)) {
        // ~54 MB path: SEG=16, GB=4, MFMA segsum + MFMA scan (MT=32)
        float* mP = (float*)d_ws;
        float* sP = mP + plane4;
        float* pP = sP + plane4;
        float* sg = pP + plane4;
        segsum_mfma_kernel<SEGS><<<grid, 256, 0, stream>>>(data, targets, W, sg);
        scan_mfma_kernel<SEGS, 4><<<grid, 256, 0, stream>>>(data, targets, W, sg, mP, sP, pP);
        combine_kernel<128><<<(BB * NN) / 4, 256, 0, stream>>>(mP, sP, pP, out);
    } else if (ws_size >= (3 * plane6 + seg16) * sizeof(float)) {
        // ~17 MB path: SEG=16, GB=6, MFMA segsum + MFMA scan
        float* mP = (float*)d_ws;
        float* sP = mP + plane6;
        float* pP = sP + plane6;
        float* sg = pP + plane6;
        segsum_mfma_kernel<SEGS><<<grid, 256, 0, stream>>>(data, targets, W, sg);
        scan_mfma_kernel<SEGS, 6><<<grid, 256, 0, stream>>>(data, targets, W, sg, mP, sP, pP);
        combine_kernel<32><<<(BB * NN) / 4, 256, 0, stream>>>(mP, sP, pP, out);
    } else {
        // 12 MB fallback: no segmentation (slow but correct)
        float* mP = (float*)d_ws;
        float* sP = mP + plane6;
        float* pP = sP + plane6;
        scan_kernel<1, 6><<<BB * CHUNKS, 256, 0, stream>>>(data, targets, W, nullptr, mP, sP, pP);
        combine_kernel<32><<<(BB * NN) / 4, 256, 0, stream>>>(mP, sP, pP, out);
    }
}

// Round 21
// 167.462 us; speedup vs baseline: 1.5885x; 1.2405x over previous
//
#include <hip/hip_runtime.h>
#include <hip/hip_bf16.h>
#include <math.h>

// Problem constants (from reference setup_inputs)
#define BB 32
#define NN 1024
#define DD 64
#define TT 2048
#define CHUNKS (TT / 256)   // 8 column-chunks of 256 (segsum geometry)
#define SEGS 16             // n-segments (decoupled scan)

typedef float f32x4 __attribute__((ext_vector_type(4)));
using s16x8 = __attribute__((ext_vector_type(8))) short;   // 8 bf16 (4 VGPRs)

// alpha in LOG2 units: exp() becomes bare v_exp_f32. Validated R9+.
#define NLOG2E_HALF (-0.72134752044448169f)   // -0.5 * log2(e)

__device__ __forceinline__ float exp2_fast(float x) {
    return __builtin_amdgcn_exp2f(x);
}

// DPP move WITHOUT tied-old operand -> fuses into the consumer op.
template<int CTRL>
__device__ __forceinline__ float dpp_mov_f(float v) {
    return __int_as_float(
        __builtin_amdgcn_mov_dpp(__float_as_int(v), CTRL, 0xF, 0xF, true));
}

template<int GB>
__device__ __forceinline__ float groupMax(float v) {
    v = fmaxf(v, dpp_mov_f<0x0B1>(v));  // xor1
    v = fmaxf(v, dpp_mov_f<0x04E>(v));  // xor2
    v = fmaxf(v, dpp_mov_f<0x141>(v));  // xor4 (row_half_mirror)
    v = fmaxf(v, dpp_mov_f<0x140>(v));  // xor8 (row_mirror)
    if constexpr (GB == 6) {
        v = fmaxf(v, __shfl_xor(v, 16));
        v = fmaxf(v, __shfl_xor(v, 32));
    }
    return v;
}

template<int GB>
__device__ __forceinline__ float groupSum(float v) {
    v += dpp_mov_f<0x0B1>(v);
    v += dpp_mov_f<0x04E>(v);
    v += dpp_mov_f<0x141>(v);
    v += dpp_mov_f<0x140>(v);
    if constexpr (GB == 6) {
        v += __shfl_xor(v, 16);
        v += __shfl_xor(v, 32);
    }
    return v;
}

// bf16 round-to-nearest-even split: x ~= hi + lo, |x-hi-lo| <= 2^-18 |x|.
__device__ __forceinline__ unsigned short bf16_rne(float x) {
    unsigned u = __float_as_uint(x);
    return (unsigned short)((u + 0x7FFFu + ((u >> 16) & 1u)) >> 16);
}
__device__ __forceinline__ void bf16_split(float x, short& hi, short& lo) {
    const unsigned short h = bf16_rne(x);
    const float xh = __uint_as_float(((unsigned)h) << 16);
    hi = (short)h;
    lo = (short)bf16_rne(x - xh);
}

__device__ __forceinline__ void loadW(const float* __restrict__ W, int col,
                                      f32x4* wv) {
#pragma unroll
    for (int i = 0; i < 16; ++i) {
        wv[i].x = W[(size_t)(4 * i + 0) * TT + col];
        wv[i].y = W[(size_t)(4 * i + 1) * TT + col];
        wv[i].z = W[(size_t)(4 * i + 2) * TT + col];
        wv[i].w = W[(size_t)(4 * i + 3) * TT + col];
    }
}

__device__ __forceinline__ float hsum(f32x4 s) {
    return (s.x + s.y) + (s.z + s.w);
}

// Scalar dot4 (fallback only).
__device__ __forceinline__ void dot4(const float* __restrict__ x0p,
                                     const f32x4* wv, float* xw) {
    const f32x4* xr0 = (const f32x4*)(x0p);
    const f32x4* xr1 = (const f32x4*)(x0p + DD);
    const f32x4* xr2 = (const f32x4*)(x0p + 2 * DD);
    const f32x4* xr3 = (const f32x4*)(x0p + 3 * DD);
    f32x4 s0 = {0.f, 0.f, 0.f, 0.f};
    f32x4 s1 = {0.f, 0.f, 0.f, 0.f};
    f32x4 s2 = {0.f, 0.f, 0.f, 0.f};
    f32x4 s3 = {0.f, 0.f, 0.f, 0.f};
#pragma unroll
    for (int i = 0; i < 16; ++i) {
        const f32x4 w = wv[i];
        s0 += xr0[i] * w;
        s1 += xr1[i] * w;
        s2 += xr2[i] * w;
        s3 += xr3[i] * w;
    }
    xw[0] = hsum(s0); xw[1] = hsum(s1); xw[2] = hsum(s2); xw[3] = hsum(s3);
}

// Load a wave's B (W) fragments for a 64-col group, hi/lo split.
// (R18/R20-verified layout: B col = base + nt*16 + (l&15),
//  k = ks*32 + (l>>4)*8 + j.)
__device__ __forceinline__ void loadB64(const float* __restrict__ W,
                                        int colbase, int l,
                                        s16x8 bh[2][4], s16x8 bl[2][4]) {
    const int c0 = colbase + (l & 15);
    const int kb = (l >> 4) * 8;
#pragma unroll
    for (int ks = 0; ks < 2; ++ks)
#pragma unroll
        for (int nt = 0; nt < 4; ++nt) {
            const int cw = c0 + nt * 16;
#pragma unroll
            for (int j = 0; j < 8; ++j) {
                short h, lo_;
                bf16_split(W[(size_t)(ks * 32 + kb + j) * TT + cw], h, lo_);
                bh[ks][nt][j] = h;
                bl[ks][nt][j] = lo_;
            }
        }
}

// MFMA a 16-row x 64-col xw tile into acc[nt] (3-product hi/lo split;
// lo*lo dropped ~2^-32). A: row = tile_n0 + (l&15), k = ks*32+(l>>4)*8+j.
__device__ __forceinline__ void mfma_tile16(const float* __restrict__ xb,
                                            int tile_n0, int l,
                                            const s16x8 bh[2][4],
                                            const s16x8 bl[2][4],
                                            f32x4 acc[4]) {
#pragma unroll
    for (int nt = 0; nt < 4; ++nt) acc[nt] = (f32x4){0.f, 0.f, 0.f, 0.f};
#pragma unroll
    for (int ks = 0; ks < 2; ++ks) {
        s16x8 ah, al;
        const int row = tile_n0 + (l & 15);
        const int kb  = ks * 32 + (l >> 4) * 8;
#pragma unroll
        for (int j = 0; j < 8; ++j) {
            short hh, ll;
            bf16_split(xb[(size_t)row * DD + kb + j], hh, ll);
            ah[j] = hh; al[j] = ll;
        }
#pragma unroll
        for (int nt = 0; nt < 4; ++nt) {
            acc[nt] = __builtin_amdgcn_mfma_f32_16x16x32_bf16(ah, bh[ks][nt], acc[nt], 0, 0, 0);
            acc[nt] = __builtin_amdgcn_mfma_f32_16x16x32_bf16(ah, bl[ks][nt], acc[nt], 0, 0, 0);
            acc[nt] = __builtin_amdgcn_mfma_f32_16x16x32_bf16(al, bh[ks][nt], acc[nt], 0, 0, 0);
        }
    }
}

// Pass A (MFMA, R20-validated): per-(b, chunk256, segment) segsum.
template<int SEG>
__global__ __launch_bounds__(256)
void segsum_mfma_kernel(const float* __restrict__ data,
                        const float* __restrict__ targets,
                        const float* __restrict__ W,
                        float* __restrict__ segsum)
{
    constexpr int NSEG = NN / SEG;            // 64
    __shared__ float ts[NSEG];

    const int blk   = blockIdx.x;
    const int s     = blk % SEG;
    const int rem   = blk / SEG;
    const int chunk = rem % CHUNKS;
    const int b     = rem / CHUNKS;
    const int tid   = threadIdx.x;
    const int wv    = tid >> 6;
    const int l     = tid & 63;

    const float* xb = data + (size_t)b * NN * DD;
    const float* tb = targets + (size_t)b * NN;
    const int n0 = s * NSEG;

    if (tid < NSEG) ts[tid] = tb[n0 + tid];

    s16x8 bh[2][4], bl[2][4];
    loadB64(W, chunk * 256 + wv * 64, l, bh, bl);
    __syncthreads();

    float colacc[4] = {0.f, 0.f, 0.f, 0.f};

#pragma unroll 1
    for (int h = 0; h < NSEG / 16; ++h) {
        f32x4 acc[4];
        mfma_tile16(xb, n0 + h * 16, l, bh, bl, acc);
#pragma unroll
        for (int r = 0; r < 4; ++r) {
            const float tv = ts[h * 16 + (l >> 4) * 4 + r];
#pragma unroll
            for (int nt = 0; nt < 4; ++nt) {
                const float d = tv - acc[nt][r];
                colacc[nt] = fmaf(d * d, NLOG2E_HALF, colacc[nt]);
            }
        }
    }

    // complete column sums across the 4 row-groups
#pragma unroll
    for (int nt = 0; nt < 4; ++nt) {
        colacc[nt] += __shfl_xor(colacc[nt], 16);
        colacc[nt] += __shfl_xor(colacc[nt], 32);
    }

    if (l < 16) {
        const size_t base = ((size_t)b * SEG + s) * TT + chunk * 256 + wv * 64 + l;
#pragma unroll
        for (int nt = 0; nt < 4; ++nt) segsum[base + nt * 16] = colacc[nt];
    }
}

// Pass B: ONE-WAVE MFMA scan, barrier-free. Each 64-thread block owns a
// (b, 64-col group, segment). Per 16-point tile: MFMA -> wave-private LDS
// (within-wave LDS ops are program-ordered; no __syncthreads needed) ->
// softmax quad loop. Removes the 4-wave barrier convergence that pinned
// occupancy at ~20% (R18-R20).
template<int SEG, int GB>
__global__ __launch_bounds__(64)
void scan_mfma1_kernel(const float* __restrict__ data,
                       const float* __restrict__ targets,
                       const float* __restrict__ W,
                       const float* __restrict__ segsum,
                       float* __restrict__ mP,
                       float* __restrict__ sP,
                       float* __restrict__ pP)
{
    constexpr int NSEG = NN / SEG;            // 64
    constexpr int MT   = 16;                  // points per tile
    constexpr int CG   = TT / 64;             // 32 col-groups
    constexpr int PPN  = TT >> GB;

    __shared__ __align__(16) float xw_tile[MT][68];   // 4.25 KB, +4 pad

    const int blk = blockIdx.x;
    const int s   = blk % SEG;
    const int rem = blk / SEG;
    const int cg  = rem % CG;
    const int b   = rem / CG;
    const int l   = threadIdx.x;              // lane (64-thread block)
    const int col = cg * 64 + l;

    const float* xb = data + (size_t)b * NN * DD;
    const float* tb = targets + (size_t)b * NN;

    s16x8 bh[2][4], bl[2][4];
    loadB64(W, cg * 64, l, bh, bl);

    const int  k16    = col >> GB;
    const bool writer = (l & ((1 << GB) - 1)) == 0;
    const size_t base0 = (size_t)b * NN * PPN + k16;

    // exclusive segment prefix (log2 units)
    float alpha = 0.0f;
    if constexpr (SEG > 1) {
        for (int s2 = 0; s2 < s; ++s2)
            alpha += segsum[((size_t)b * SEG + s2) * TT + col];
    }

    const int n0 = s * NSEG;

#pragma unroll 1
    for (int h = 0; h < NSEG / MT; ++h) {
        // ---------- phase A: MFMA 16x64 xw tile ----------
        f32x4 acc[4];
        mfma_tile16(xb, n0 + h * MT, l, bh, bl, acc);

        // C -> wave-private LDS (row = (l>>4)*4 + r, col = nt*16 + (l&15))
#pragma unroll
        for (int nt = 0; nt < 4; ++nt)
#pragma unroll
            for (int r = 0; r < 4; ++r)
                xw_tile[(l >> 4) * 4 + r][nt * 16 + (l & 15)] = acc[nt][r];

        // ---------- phase B: softmax for these 16 points ----------
#pragma unroll 1
        for (int q = 0; q < MT; q += 4) {
            const int n = n0 + h * MT + q;
            float xw[4];
#pragma unroll
            for (int j = 0; j < 4; ++j) xw[j] = xw_tile[q + j][l];

            float a[4];
            float al_ = alpha;
#pragma unroll
            for (int j = 0; j < 4; ++j) {
                a[j] = al_;
                const float d = tb[n + j] - xw[j];
                al_ = fmaf(d * d, NLOG2E_HALF, al_);
            }
            alpha = al_;

            float m[4], e[4], qv[4], sv[4], pv[4];
#pragma unroll
            for (int j = 0; j < 4; ++j) m[j] = groupMax<GB>(a[j]);
#pragma unroll
            for (int j = 0; j < 4; ++j) {
                e[j]  = exp2_fast(a[j] - m[j]);
                qv[j] = e[j] * xw[j];
            }
#pragma unroll
            for (int j = 0; j < 4; ++j) sv[j] = groupSum<GB>(e[j]);
#pragma unroll
            for (int j = 0; j < 4; ++j) pv[j] = groupSum<GB>(qv[j]);

            if (writer) {
                const size_t i0 = base0 + (size_t)n * PPN;
#pragma unroll
                for (int j = 0; j < 4; ++j) {
                    mP[i0 + (size_t)j * PPN] = m[j];
                    sP[i0 + (size_t)j * PPN] = sv[j];
                    pP[i0 + (size_t)j * PPN] = pv[j];
                }
            }
        }
        // no barrier: next tile's LDS writes are ordered after these reads
        // within the single wave (compiler inserts lgkmcnt waits).
    }
}

// Single-stream scalar scan (fallback path only; R14 form).
template<int SEG, int GB>
__global__ __launch_bounds__(256, 4)
void scan_kernel(const float* __restrict__ data,
                 const float* __restrict__ targets,
                 const float* __restrict__ W,
                 const float* __restrict__ segsum,
                 float* __restrict__ mP,
                 float* __restrict__ sP,
                 float* __restrict__ pP)
{
    constexpr int NSEG = NN / SEG;
    constexpr int PPN  = TT >> GB;
    const int blk   = blockIdx.x;
    const int s     = blk % SEG;
    const int rem   = blk / SEG;
    const int chunk = rem % CHUNKS;
    const int b     = rem / CHUNKS;
    const int tid   = threadIdx.x;
    const int lane  = tid & 63;
    const int col   = chunk * 256 + tid;

    f32x4 wv[16];
    loadW(W, col, wv);

    const float* xb = data + (size_t)b * NN * DD;
    const float* tb = targets + (size_t)b * NN;

    const int  k      = (chunk * 256 + (tid & ~((1 << GB) - 1))) >> GB;
    const bool writer = (lane & ((1 << GB) - 1)) == 0;
    const size_t base0 = (size_t)b * NN * PPN + k;

    float alpha = 0.0f;
    if constexpr (SEG > 1) {
        for (int s2 = 0; s2 < s; ++s2)
            alpha += segsum[((size_t)b * SEG + s2) * TT + col];
    }

    const int n0 = s * NSEG;
    for (int n = n0; n < n0 + NSEG; n += 4) {
        float xw[4];
        dot4(xb + (size_t)n * DD, wv, xw);
        float a[4];
        float al = alpha;
#pragma unroll
        for (int j = 0; j < 4; ++j) {
            a[j] = al;
            const float d = tb[n + j] - xw[j];
            al = fmaf(d * d, NLOG2E_HALF, al);
        }
        alpha = al;
        float m[4], e[4], qv[4], sv[4], pv[4];
#pragma unroll
        for (int j = 0; j < 4; ++j) m[j] = groupMax<GB>(a[j]);
#pragma unroll
        for (int j = 0; j < 4; ++j) {
            e[j]  = exp2_fast(a[j] - m[j]);
            qv[j] = e[j] * xw[j];
        }
#pragma unroll
        for (int j = 0; j < 4; ++j) sv[j] = groupSum<GB>(e[j]);
#pragma unroll
        for (int j = 0; j < 4; ++j) pv[j] = groupSum<GB>(qv[j]);
        if (writer) {
            const size_t i0 = base0 + (size_t)n * PPN;
#pragma unroll
            for (int j = 0; j < 4; ++j) {
                mP[i0 + (size_t)j * PPN] = m[j];
                sP[i0 + (size_t)j * PPN] = sv[j];
                pP[i0 + (size_t)j * PPN] = pv[j];
            }
        }
    }
}

// Pass C: one wave per (b,n): merge PPN partials (log2 units).
template<int PPN>
__global__ __launch_bounds__(256)
void combine_kernel(const float* __restrict__ mP,
                    const float* __restrict__ sP,
                    const float* __restrict__ pP,
                    float* __restrict__ out)
{
    const int wgid = blockIdx.x * 4 + (threadIdx.x >> 6);   // = b*NN + n
    const int lane = threadIdx.x & 63;
    const size_t base = (size_t)wgid * PPN;

    float m = -INFINITY, s = 0.0f, p = 0.0f;
    if constexpr (PPN >= 64) {
#pragma unroll
        for (int j = 0; j < PPN / 64; ++j) {
            const size_t idx = base + lane + j * 64;
            const float mk = mP[idx], sk = sP[idx], pk = pP[idx];
            const float M  = fmaxf(m, mk);
            const float e1 = exp2_fast(m - M), e2 = exp2_fast(mk - M);
            s = s * e1 + sk * e2;
            p = p * e1 + pk * e2;
            m = M;
        }
    } else {
        if (lane < PPN) {
            m = mP[base + lane]; s = sP[base + lane]; p = pP[base + lane];
        }
    }

#pragma unroll
    for (int off = 1; off < 64; off <<= 1) {
        const float mo = __shfl_xor(m, off);
        const float so = __shfl_xor(s, off);
        const float po = __shfl_xor(p, off);
        const float M  = fmaxf(m, mo);
        const float e1 = exp2_fast(m - M), e2 = exp2_fast(mo - M);
        s = s * e1 + so * e2;
        p = p * e1 + po * e2;
        m = M;
    }

    if (lane == 0) out[wgid] = p / s;
}

extern "C" void kernel_launch(void* const* d_in, const int* in_sizes, int n_in,
                              void* d_out, int out_size, void* d_ws, size_t ws_size,
                              hipStream_t stream)
{
    (void)in_sizes; (void)n_in; (void)out_size;
    const float* data    = (const float*)d_in[0];
    const float* targets = (const float*)d_in[1];
    const float* W       = (const float*)d_in[2];
    float* out = (float*)d_out;

    const size_t plane4 = (size_t)BB * NN * (TT >> 4);   // GB=4: 128 partials/(b,n)
    const size_t plane6 = (size_t)BB * NN * (TT >> 6);   // GB=6: 32 partials/(b,n)
    const size_t seg16  = (size_t)BB * SEGS * TT;

    const int seg_grid  = BB * SEGS * CHUNKS;            // 4096 blocks of 256
    const int scan_grid = BB * (TT / 64) * SEGS;         // 16384 blocks of 64

    if (ws_size >= (3 * plane4 + seg16) * sizeof(float)) {
        // ~54 MB path: SEG=16, GB=4, MFMA segsum + 1-wave MFMA scan
        float* mP = (float*)d_ws;
        float* sP = mP + plane4;
        float* pP = sP + plane4;
        float* sg = pP + plane4;
        segsum_mfma_kernel<SEGS><<<seg_grid, 256, 0, stream>>>(data, targets, W, sg);
        scan_mfma1_kernel<SEGS, 4><<<scan_grid, 64, 0, stream>>>(data, targets, W, sg, mP, sP, pP);
        combine_kernel<128><<<(BB * NN) / 4, 256, 0, stream>>>(mP, sP, pP, out);
    } else if (ws_size >= (3 * plane6 + seg16) * sizeof(float)) {
        // ~17 MB path: SEG=16, GB=6
        float* mP = (float*)d_ws;
        float* sP = mP + plane6;
        float* pP = sP + plane6;
        float* sg = pP + plane6;
        segsum_mfma_kernel<SEGS><<<seg_grid, 256, 0, stream>>>(data, targets, W, sg);
        scan_mfma1_kernel<SEGS, 6><<<scan_grid, 64, 0, stream>>>(data, targets, W, sg, mP, sP, pP);
        combine_kernel<32><<<(BB * NN) / 4, 256, 0, stream>>>(mP, sP, pP, out);
    } else {
        // 12 MB fallback: no segmentation (slow but correct)
        float* mP = (float*)d_ws;
        float* sP = mP + plane6;
        float* pP = sP + plane6;
        scan_kernel<1, 6><<<BB * CHUNKS, 256, 0, stream>>>(data, targets, W, nullptr, mP, sP, pP);
        combine_kernel<32><<<(BB * NN) / 4, 256, 0, stream>>>(mP, sP, pP, out);
    }
}